// Round 5
// baseline (293.747 us; speedup 1.0000x reference)
//
#include <hip/hip_runtime.h>
#include <hip/hip_bf16.h>
#include <math.h>

#define BB 4
#define CC 64
#define OO 64
#define HH 96
#define WW 320
#define HWP (HH*WW)   // 30720
#define NPIX (BB*HWP) // 122880

typedef __attribute__((ext_vector_type(8))) short bf16x8;
typedef __attribute__((ext_vector_type(8))) unsigned short u16x8;
typedef __attribute__((ext_vector_type(4))) float f32x4;

__device__ inline unsigned short f2bf(float f) {
    unsigned int u = __float_as_uint(f);
    u = (u + 0x7FFFu + ((u >> 16) & 1u)) >> 16;
    return (unsigned short)u;
}
__device__ inline float bf2f(unsigned short s) {
    return __uint_as_float(((unsigned int)s) << 16);
}

// ---------------------------------------------------------------------------
// K_prep: all bf16 weight repacks + (last block) global MLP -> Gsum.
//  cwT  [9][64 o][64 ci]  <- conv_w
//  Wlm  [9][48 r][64 ci]  <- rows 0-31 loc_w1, 32-40 mask_w, 41-47 zero
//  lw2T [32][32]          <- loc_w2
//  Wf   [9][32 o][32 cl]  <- fuse_w1 l-channels
//  fw2A [32][32]          <- rows 0-17 fuse_w2, rest zero
// ---------------------------------------------------------------------------
#define PREP_N (36864 + 27648 + 1024 + 9216 + 1024)
#define PREP_BLOCKS ((PREP_N + 255) / 256)
__global__ void k_prep(const float* __restrict__ cw,
                       const float* __restrict__ lw1, const float* __restrict__ mw,
                       const float* __restrict__ lw2,
                       const float* __restrict__ fw1, const float* __restrict__ fw2,
                       const float* __restrict__ sb,
                       const float* __restrict__ gw1, const float* __restrict__ gb1,
                       const float* __restrict__ gw2, const float* __restrict__ gb2,
                       unsigned short* __restrict__ cwT,
                       unsigned short* __restrict__ Wlm,
                       unsigned short* __restrict__ lw2T,
                       unsigned short* __restrict__ Wf,
                       unsigned short* __restrict__ fw2A,
                       float* __restrict__ gsum) {
    __shared__ float g_s[BB * 32];
    int tid = threadIdx.x;
    if (blockIdx.x == PREP_BLOCKS) {
        // global MLP block
        if (tid < 128) {
            int b = tid >> 5, i = tid & 31;
            float b0 = sb[b * 5 + 4] - sb[b * 5 + 2];
            float b1 = sb[b * 5 + 3] - sb[b * 5 + 1];
            float acc = gb2[i];
            for (int j = 0; j < 64; ++j) {
                float h1 = b0 * gw1[j * 2 + 0] + b1 * gw1[j * 2 + 1] + gb1[j];
                h1 = fmaxf(h1, 0.f);
                acc += gw2[i * 64 + j] * h1;
            }
            g_s[b * 32 + i] = acc;
        }
        __syncthreads();
        for (int e = tid; e < BB * 32 * 9; e += 256) {
            int b = e / 288, r = e % 288, o = r / 9, k = r % 9;
            float s = 0.f;
            for (int ci = 0; ci < 32; ++ci)
                s += g_s[b * 32 + ci] * fw1[o * 576 + ci * 9 + k];
            gsum[e] = s;
        }
        return;
    }
    int e = blockIdx.x * 256 + tid;
    if (e < 36864) {
        int k = e >> 12, r = e & 4095, o = r >> 6, ci = r & 63;
        cwT[e] = f2bf(cw[o * 576 + ci * 9 + k]);
        return;
    }
    e -= 36864;
    if (e < 27648) {
        int k = e / 3072, r = e % 3072, row = r >> 6, ci = r & 63;
        float v = 0.f;
        if (row < 32) v = lw1[row * 576 + ci * 9 + k];
        else if (row < 41) v = mw[(row - 32) * 576 + ci * 9 + k];
        Wlm[e] = f2bf(v);
        return;
    }
    e -= 27648;
    if (e < 1024) { lw2T[e] = f2bf(lw2[e]); return; }
    e -= 1024;
    if (e < 9216) {
        int k = e >> 10, r = e & 1023, o = r >> 5, cl = r & 31;
        Wf[e] = f2bf(fw1[o * 576 + (32 + cl) * 9 + k]);
        return;
    }
    e -= 9216;
    if (e < 1024) {
        int m = e >> 5, ci = e & 31;
        fw2A[e] = f2bf(m < 18 ? fw2[m * 32 + ci] : 0.f);
    }
}

// ---------------------------------------------------------------------------
// K_xT: NCHW f32 -> NHWC bf16. Block = 64 px x 64 ci.
// Phase1: float4 global loads (4 px, 1 ci) -> b64 LDS writes ([ci][px]).
// Phase2: gather 16 b16 LDS reads per thread -> 16B coalesced global stores.
// ---------------------------------------------------------------------------
__global__ __launch_bounds__(256) void k_xT(const float* __restrict__ x,
                                            unsigned short* __restrict__ xT) {
    __shared__ unsigned short Ls[64 * 68];  // [ci][px], pad 68
    int tid = threadIdx.x;
    int p0 = blockIdx.x * 64;
    int b = p0 / HWP;
    int rem0 = p0 % HWP;
    const float* xb = x + (size_t)b * CC * HWP + rem0;
    int px4 = (tid & 15) * 4;
    int cib = tid >> 4;   // 0..15
#pragma unroll
    for (int it = 0; it < 4; ++it) {
        int ci = it * 16 + cib;
        float4 v = *(const float4*)&xb[(size_t)ci * HWP + px4];
        ushort4 u;
        u.x = f2bf(v.x); u.y = f2bf(v.y); u.z = f2bf(v.z); u.w = f2bf(v.w);
        *(ushort4*)&Ls[ci * 68 + px4] = u;
    }
    __syncthreads();
    int px = tid & 63;
    int cg = tid >> 6;    // 0..3
#pragma unroll
    for (int j = 0; j < 2; ++j) {
        int ci0 = cg * 16 + j * 8;
        u16x8 r;
#pragma unroll
        for (int i = 0; i < 8; ++i) r[i] = Ls[(ci0 + i) * 68 + px];
        *(u16x8*)&xT[((size_t)p0 + px) * 64 + ci0] = r;
    }
}

// ---------------------------------------------------------------------------
// K2: loc+mask as MFMA implicit GEMM. Block = 256 thr = 128 px.
// GEMM1: M=48 (32 loc1 + 9 mask + pad), K=576 (9 taps x 64 ci), N=128 px.
// Then relu -> LDS, GEMM2: l = lw2 (32x32) x relu(l1). mask -> sigmoid -> bf16.
// Outputs: lT NHWC bf16 [p][32], mbuf bf16 [k][p].
// ---------------------------------------------------------------------------
__global__ __launch_bounds__(256) void k_locmask(
        const unsigned short* __restrict__ xT,
        const unsigned short* __restrict__ Wlm,
        const unsigned short* __restrict__ lw2T,
        const float* __restrict__ lb1, const float* __restrict__ lb2,
        const float* __restrict__ mb,
        unsigned short* __restrict__ lT, unsigned short* __restrict__ mbuf) {
    __shared__ unsigned short Vs[128 * 72];
    __shared__ unsigned short Ws[48 * 72];
    __shared__ unsigned short VsL[128 * 40];
    __shared__ unsigned short W2[32 * 40];

    int tid = threadIdx.x;
    int p0 = blockIdx.x * 128;
    int rem0 = p0 % HWP;

    int lane = tid & 63, wv = tid >> 6;
    int lr = lane & 15, lq = lane >> 4;
    int n0 = wv * 32;

    int spx = tid >> 1;      // staging pixel 0..127
    int shf = tid & 1;       // ci half
    int sy = (rem0 + spx) / WW;
    int sx = (rem0 + spx) % WW;

    f32x4 acc[3][2];
#pragma unroll
    for (int mt = 0; mt < 3; ++mt)
#pragma unroll
        for (int t = 0; t < 2; ++t) acc[mt][t] = (f32x4){0.f, 0.f, 0.f, 0.f};

    for (int k = 0; k < 9; ++k) {
        int dy = k / 3 - 1, dx = k % 3 - 1;
        __syncthreads();
#pragma unroll
        for (int c = tid; c < 384; c += 256) {
            int row = c >> 3, g = c & 7;
            *(float4*)&Ws[row * 72 + g * 8] =
                *(const float4*)&Wlm[((size_t)k * 48 + row) * 64 + g * 8];
        }
        {
            int yy = sy + dy, xw = sx + dx;
            bool valid = (yy >= 0) && (yy < HH) && (xw >= 0) && (xw < WW);
            unsigned short* dst = &Vs[spx * 72 + shf * 32];
            if (valid) {
                const unsigned short* src =
                    xT + ((size_t)(p0 + spx) + (dy * WW + dx)) * 64 + shf * 32;
#pragma unroll
                for (int j = 0; j < 4; ++j)
                    *(float4*)(dst + j * 8) = *(const float4*)(src + j * 8);
            } else {
                float4 z = {0.f, 0.f, 0.f, 0.f};
#pragma unroll
                for (int j = 0; j < 4; ++j) *(float4*)(dst + j * 8) = z;
            }
        }
        __syncthreads();
#pragma unroll
        for (int h = 0; h < 2; ++h) {
            bf16x8 b0 = *(const bf16x8*)&Vs[(n0 + lr) * 72 + h * 32 + lq * 8];
            bf16x8 b1 = *(const bf16x8*)&Vs[(n0 + 16 + lr) * 72 + h * 32 + lq * 8];
#pragma unroll
            for (int mt = 0; mt < 3; ++mt) {
                bf16x8 a = *(const bf16x8*)&Ws[(mt * 16 + lr) * 72 + h * 32 + lq * 8];
                acc[mt][0] = __builtin_amdgcn_mfma_f32_16x16x32_bf16(a, b0, acc[mt][0], 0, 0, 0);
                acc[mt][1] = __builtin_amdgcn_mfma_f32_16x16x32_bf16(a, b1, acc[mt][1], 0, 0, 0);
            }
        }
    }

#pragma unroll
    for (int c = tid; c < 128; c += 256) {
        int row = c >> 2, g = c & 3;
        *(float4*)&W2[row * 40 + g * 8] = *(const float4*)&lw2T[row * 32 + g * 8];
    }
#pragma unroll
    for (int mt = 0; mt < 2; ++mt)
#pragma unroll
        for (int t = 0; t < 2; ++t)
#pragma unroll
            for (int r = 0; r < 4; ++r) {
                int m = mt * 16 + lq * 4 + r;
                float v = acc[mt][t][r] + lb1[m];
                VsL[(n0 + t * 16 + lr) * 40 + m] = f2bf(fmaxf(v, 0.f));
            }
#pragma unroll
    for (int t = 0; t < 2; ++t)
#pragma unroll
        for (int r = 0; r < 4; ++r) {
            int j = lq * 4 + r;
            if (j < 9) {
                float v = acc[2][t][r] + mb[j];
                v = 1.f / (1.f + __expf(-v));
                mbuf[(size_t)j * NPIX + p0 + n0 + t * 16 + lr] = f2bf(v);
            }
        }
    __syncthreads();
    f32x4 acc2[2][2];
#pragma unroll
    for (int mt = 0; mt < 2; ++mt)
#pragma unroll
        for (int t = 0; t < 2; ++t) acc2[mt][t] = (f32x4){0.f, 0.f, 0.f, 0.f};
#pragma unroll
    for (int t = 0; t < 2; ++t) {
        bf16x8 b2 = *(const bf16x8*)&VsL[(n0 + t * 16 + lr) * 40 + lq * 8];
#pragma unroll
        for (int mt = 0; mt < 2; ++mt) {
            bf16x8 a2 = *(const bf16x8*)&W2[(mt * 16 + lr) * 40 + lq * 8];
            acc2[mt][t] = __builtin_amdgcn_mfma_f32_16x16x32_bf16(a2, b2, acc2[mt][t], 0, 0, 0);
        }
    }
    __syncthreads();  // Vs reuse as [px][40] shuffle buffer
#pragma unroll
    for (int mt = 0; mt < 2; ++mt)
#pragma unroll
        for (int t = 0; t < 2; ++t)
#pragma unroll
            for (int r = 0; r < 4; ++r) {
                int m = mt * 16 + lq * 4 + r;
                Vs[(n0 + t * 16 + lr) * 40 + m] = f2bf(acc2[mt][t][r] + lb2[m]);
            }
    __syncthreads();
    {
        int px = tid >> 1, hf = tid & 1;
        float4 v0 = *(const float4*)&Vs[px * 40 + hf * 16];
        float4 v1 = *(const float4*)&Vs[px * 40 + hf * 16 + 8];
        unsigned short* dst = lT + (size_t)(p0 + px) * 32 + hf * 16;
        *(float4*)dst = v0;
        *(float4*)(dst + 8) = v1;
    }
}

// ---------------------------------------------------------------------------
// K3: fuse conv as MFMA implicit GEMM. M=32 f, K=288, N=128.
// GEMM2: offset = fw2 x relu(f). Writes dA: packed bf16 (dy,dx) per (k,p).
// ---------------------------------------------------------------------------
__global__ __launch_bounds__(256) void k_fuse(
        const unsigned short* __restrict__ lT,
        const float* __restrict__ gsum,
        const unsigned short* __restrict__ Wf,
        const unsigned short* __restrict__ fw2A,
        const float* __restrict__ fb1, const float* __restrict__ fb2,
        unsigned int* __restrict__ dA) {
    __shared__ unsigned short Vs[128 * 40];
    __shared__ unsigned short Ws[32 * 40];
    __shared__ unsigned short VsF[128 * 40];
    __shared__ unsigned short W2[32 * 40];
    __shared__ float gs[288];

    int tid = threadIdx.x;
    int p0 = blockIdx.x * 128;
    int b = p0 / HWP;
    int rem0 = p0 % HWP;

    int lane = tid & 63, wv = tid >> 6;
    int lr = lane & 15, lq = lane >> 4;
    int n0 = wv * 32;

    int spx = tid >> 1;
    int shf = tid & 1;
    int sy = (rem0 + spx) / WW;
    int sx = (rem0 + spx) % WW;

    for (int e = tid; e < 288; e += 256) gs[e] = gsum[b * 288 + e];

    f32x4 acc[2][2];
#pragma unroll
    for (int mt = 0; mt < 2; ++mt)
#pragma unroll
        for (int t = 0; t < 2; ++t) acc[mt][t] = (f32x4){0.f, 0.f, 0.f, 0.f};

    for (int k = 0; k < 9; ++k) {
        int dy = k / 3 - 1, dx = k % 3 - 1;
        __syncthreads();
#pragma unroll
        for (int c = tid; c < 128; c += 256) {
            int row = c >> 2, g = c & 3;
            *(float4*)&Ws[row * 40 + g * 8] =
                *(const float4*)&Wf[((size_t)k * 32 + row) * 32 + g * 8];
        }
        {
            int yy = sy + dy, xw = sx + dx;
            bool valid = (yy >= 0) && (yy < HH) && (xw >= 0) && (xw < WW);
            unsigned short* dst = &Vs[spx * 40 + shf * 16];
            if (valid) {
                const unsigned short* src =
                    lT + ((size_t)(p0 + spx) + (dy * WW + dx)) * 32 + shf * 16;
                *(float4*)dst = *(const float4*)src;
                *(float4*)(dst + 8) = *(const float4*)(src + 8);
            } else {
                float4 z = {0.f, 0.f, 0.f, 0.f};
                *(float4*)dst = z;
                *(float4*)(dst + 8) = z;
            }
        }
        __syncthreads();
#pragma unroll
        for (int t = 0; t < 2; ++t) {
            bf16x8 bfr = *(const bf16x8*)&Vs[(n0 + t * 16 + lr) * 40 + lq * 8];
#pragma unroll
            for (int mt = 0; mt < 2; ++mt) {
                bf16x8 a = *(const bf16x8*)&Ws[(mt * 16 + lr) * 40 + lq * 8];
                acc[mt][t] = __builtin_amdgcn_mfma_f32_16x16x32_bf16(a, bfr, acc[mt][t], 0, 0, 0);
            }
        }
    }

#pragma unroll
    for (int c = tid; c < 128; c += 256) {
        int row = c >> 2, g = c & 3;
        *(float4*)&W2[row * 40 + g * 8] = *(const float4*)&fw2A[row * 32 + g * 8];
    }
#pragma unroll
    for (int t = 0; t < 2; ++t) {
        int px = n0 + t * 16 + lr;
        int rem = rem0 + px;
        int y = rem / WW, xx = rem % WW;
        bool vk[9];
#pragma unroll
        for (int k = 0; k < 9; ++k) {
            int yy = y + k / 3 - 1, xw = xx + k % 3 - 1;
            vk[k] = (yy >= 0) && (yy < HH) && (xw >= 0) && (xw < WW);
        }
#pragma unroll
        for (int mt = 0; mt < 2; ++mt)
#pragma unroll
            for (int r = 0; r < 4; ++r) {
                int m = mt * 16 + lq * 4 + r;
                float s = fb1[m];
#pragma unroll
                for (int k = 0; k < 9; ++k)
                    if (vk[k]) s += gs[m * 9 + k];
                float v = acc[mt][t][r] + s;
                VsF[px * 40 + m] = f2bf(fmaxf(v, 0.f));
            }
    }
    __syncthreads();
    f32x4 acc3[2][2];
#pragma unroll
    for (int mt = 0; mt < 2; ++mt)
#pragma unroll
        for (int t = 0; t < 2; ++t) acc3[mt][t] = (f32x4){0.f, 0.f, 0.f, 0.f};
#pragma unroll
    for (int t = 0; t < 2; ++t) {
        bf16x8 b2 = *(const bf16x8*)&VsF[(n0 + t * 16 + lr) * 40 + lq * 8];
#pragma unroll
        for (int mt = 0; mt < 2; ++mt) {
            bf16x8 a2 = *(const bf16x8*)&W2[(mt * 16 + lr) * 40 + lq * 8];
            acc3[mt][t] = __builtin_amdgcn_mfma_f32_16x16x32_bf16(a2, b2, acc3[mt][t], 0, 0, 0);
        }
    }
    // write packed bf16 (dy,dx): lane holds m and m+1 in adjacent regs (rr even)
#pragma unroll
    for (int t = 0; t < 2; ++t) {
        int p = p0 + n0 + t * 16 + lr;
#pragma unroll
        for (int mt = 0; mt < 2; ++mt)
#pragma unroll
            for (int rr = 0; rr < 4; rr += 2) {
                int m = mt * 16 + lq * 4 + rr;
                if (m < 18) {
                    float dyv = acc3[mt][t][rr] + fb2[m];
                    float dxv = acc3[mt][t][rr + 1] + fb2[m + 1];
                    dA[(size_t)(m >> 1) * NPIX + p] =
                        (unsigned)f2bf(dyv) | ((unsigned)f2bf(dxv) << 16);
                }
            }
    }
}

// ---------------------------------------------------------------------------
// K4: deformable conv — LDS-free, barrier-free MFMA implicit GEMM.
// Block = 256 thr = 4 waves; wave wv owns px-tile [p0+wv*16, +16).
// Each lane builds its own B-fragment (bilinear interp of 8 channels from
// NHWC-bf16 xT) in registers; A-fragments load from L2-hot cwT.
// ---------------------------------------------------------------------------
__global__ __launch_bounds__(256) void k_deform(
        const unsigned short* __restrict__ xT,
        const unsigned short* __restrict__ cwT, const float* __restrict__ cb,
        const unsigned int* __restrict__ dA,
        const unsigned short* __restrict__ mA, float* __restrict__ out) {
    int tid = threadIdx.x;
    int p0 = blockIdx.x * 64;
    int b = p0 / HWP;
    int rem0 = p0 % HWP;
    int lane = tid & 63;
    int wv = tid >> 6;
    int lr = lane & 15;
    int lq = lane >> 4;
    int px = wv * 16 + lr;
    int p = p0 + px;
    int rem = rem0 + px;
    int y = rem / WW, xx = rem % WW;
    const unsigned short* xTb = xT + (size_t)b * HWP * 64;

    f32x4 acc[4];
#pragma unroll
    for (int mt = 0; mt < 4; ++mt) {
#pragma unroll
        for (int r = 0; r < 4; ++r) acc[mt][r] = cb[mt * 16 + lq * 4 + r];
    }

    // prefetch all per-pixel tap parameters
    unsigned int duA[9];
    float mkA[9];
#pragma unroll
    for (int k = 0; k < 9; ++k) {
        duA[k] = dA[(size_t)k * NPIX + p];
        mkA[k] = bf2f(mA[(size_t)k * NPIX + p]);
    }

    for (int k = 0; k < 9; ++k) {
        float mk = mkA[k];
        float ys = (float)(y + k / 3 - 1) + bf2f((unsigned short)(duA[k] & 0xffffu));
        float xs = (float)(xx + k % 3 - 1) + bf2f((unsigned short)(duA[k] >> 16));
        float y0f = floorf(ys), x0f = floorf(xs);
        int y0 = (int)y0f, x0 = (int)x0f;
        float wy = ys - y0f, wx = xs - x0f;
        float c00 = (1.f - wy) * (1.f - wx) * mk;
        float c01 = (1.f - wy) * wx * mk;
        float c10 = wy * (1.f - wx) * mk;
        float c11 = wy * wx * mk;
        bool vy0 = (y0 >= 0) && (y0 < HH);
        bool vy1 = (y0 + 1 >= 0) && (y0 + 1 < HH);
        bool vx0 = (x0 >= 0) && (x0 < WW);
        bool vx1 = (x0 + 1 >= 0) && (x0 + 1 < WW);
        c00 = (vy0 && vx0) ? c00 : 0.f;
        c01 = (vy0 && vx1) ? c01 : 0.f;
        c10 = (vy1 && vx0) ? c10 : 0.f;
        c11 = (vy1 && vx1) ? c11 : 0.f;
        int yc0 = min(max(y0, 0), HH - 1), yc1 = min(max(y0 + 1, 0), HH - 1);
        int xc0 = min(max(x0, 0), WW - 1), xc1 = min(max(x0 + 1, 0), WW - 1);
        int i00 = (yc0 * WW + xc0) * 64, i01 = (yc0 * WW + xc1) * 64;
        int i10 = (yc1 * WW + xc0) * 64, i11 = (yc1 * WW + xc1) * 64;

#pragma unroll
        for (int h = 0; h < 2; ++h) {
            int cb_ = h * 32 + lq * 8;
            u16x8 s00 = *(const u16x8*)(xTb + i00 + cb_);
            u16x8 s01 = *(const u16x8*)(xTb + i01 + cb_);
            u16x8 s10 = *(const u16x8*)(xTb + i10 + cb_);
            u16x8 s11 = *(const u16x8*)(xTb + i11 + cb_);
            bf16x8 bfrag;
#pragma unroll
            for (int j = 0; j < 8; ++j) {
                float v = c00 * bf2f(s00[j]) + c01 * bf2f(s01[j]) +
                          c10 * bf2f(s10[j]) + c11 * bf2f(s11[j]);
                bfrag[j] = (short)f2bf(v);
            }
            const unsigned short* wk = cwT + (size_t)k * 4096 + cb_;
#pragma unroll
            for (int mt = 0; mt < 4; ++mt) {
                bf16x8 a = *(const bf16x8*)&wk[(mt * 16 + lr) * 64];
                acc[mt] = __builtin_amdgcn_mfma_f32_16x16x32_bf16(a, bfrag, acc[mt], 0, 0, 0);
            }
        }
    }

#pragma unroll
    for (int mt = 0; mt < 4; ++mt) {
#pragma unroll
        for (int r = 0; r < 4; ++r) {
            int o = mt * 16 + lq * 4 + r;
            out[(size_t)(b * 64 + o) * HWP + rem] = acc[mt][r];
        }
    }
}

// ---------------------------------------------------------------------------
extern "C" void kernel_launch(void* const* d_in, const int* in_sizes, int n_in,
                              void* d_out, int out_size, void* d_ws, size_t ws_size,
                              hipStream_t stream) {
    const float* x   = (const float*)d_in[0];
    const float* sb  = (const float*)d_in[1];
    const float* gw1 = (const float*)d_in[2];
    const float* gb1 = (const float*)d_in[3];
    const float* gw2 = (const float*)d_in[4];
    const float* gb2 = (const float*)d_in[5];
    const float* lw1 = (const float*)d_in[6];
    const float* lb1 = (const float*)d_in[7];
    const float* lw2 = (const float*)d_in[8];
    const float* lb2 = (const float*)d_in[9];
    const float* fw1 = (const float*)d_in[10];
    const float* fb1 = (const float*)d_in[11];
    const float* fw2 = (const float*)d_in[12];
    const float* fb2 = (const float*)d_in[13];
    const float* mw  = (const float*)d_in[14];
    const float* mb  = (const float*)d_in[15];
    const float* cw  = (const float*)d_in[16];
    const float* cb  = (const float*)d_in[17];
    float* out = (float*)d_out;

    char* w = (char*)d_ws;
    float* gsum = (float*)w;                   w += 1152 * 4;
    unsigned short* cwT  = (unsigned short*)w; w += 36864 * 2;
    unsigned short* Wlm  = (unsigned short*)w; w += 27648 * 2;
    unsigned short* lw2T = (unsigned short*)w; w += 1024 * 2;
    unsigned short* Wf   = (unsigned short*)w; w += 9216 * 2;
    unsigned short* fw2A = (unsigned short*)w; w += 1024 * 2;
    unsigned short* mbuf = (unsigned short*)w; w += (size_t)9 * NPIX * 2;
    unsigned int* dA = (unsigned int*)w;       w += (size_t)9 * NPIX * 4;
    unsigned short* xT = (unsigned short*)w;   w += (size_t)NPIX * 64 * 2;
    unsigned short* lT = (unsigned short*)w;

    k_prep<<<PREP_BLOCKS + 1, 256, 0, stream>>>(cw, lw1, mw, lw2, fw1, fw2,
                                                sb, gw1, gb1, gw2, gb2,
                                                cwT, Wlm, lw2T, Wf, fw2A, gsum);
    k_xT<<<NPIX / 64, 256, 0, stream>>>(x, xT);
    k_locmask<<<NPIX / 128, 256, 0, stream>>>(xT, Wlm, lw2T, lb1, lb2, mb, lT, mbuf);
    k_fuse<<<NPIX / 128, 256, 0, stream>>>(lT, gsum, Wf, fw2A, fb1, fb2, dA);
    k_deform<<<NPIX / 64, 256, 0, stream>>>(xT, cwT, cb, dA, mbuf, out);
}

// Round 8
// 216.631 us; speedup vs baseline: 1.3560x; 1.3560x over previous
//
#include <hip/hip_runtime.h>
#include <hip/hip_bf16.h>
#include <math.h>

#define BB 4
#define CC 64
#define OO 64
#define HH 96
#define WW 320
#define HWP (HH*WW)   // 30720
#define NPIX (BB*HWP) // 122880

typedef __attribute__((ext_vector_type(8))) short bf16x8;
typedef __attribute__((ext_vector_type(8))) unsigned short u16x8;
typedef __attribute__((ext_vector_type(4))) float f32x4;

__device__ inline unsigned short f2bf(float f) {
    unsigned int u = __float_as_uint(f);
    u = (u + 0x7FFFu + ((u >> 16) & 1u)) >> 16;
    return (unsigned short)u;
}
__device__ inline float bf2f(unsigned short s) {
    return __uint_as_float(((unsigned int)s) << 16);
}

// ---------------------------------------------------------------------------
// K_prep: all bf16 weight repacks in one launch.
//  cwT  [9][64 o][64 ci]  <- conv_w
//  Wlm  [9][48 r][64 ci]  <- rows 0-31 loc_w1, 32-40 mask_w, 41-47 zero
//  lw2T [32][32]          <- loc_w2
//  Wf   [9][32 o][32 cl]  <- fuse_w1 l-channels
//  fw2A [32][32]          <- rows 0-17 fuse_w2, rest zero
// ---------------------------------------------------------------------------
#define PREP_N (36864 + 27648 + 1024 + 9216 + 1024)
__global__ void k_prep(const float* __restrict__ cw,
                       const float* __restrict__ lw1, const float* __restrict__ mw,
                       const float* __restrict__ lw2,
                       const float* __restrict__ fw1, const float* __restrict__ fw2,
                       unsigned short* __restrict__ cwT,
                       unsigned short* __restrict__ Wlm,
                       unsigned short* __restrict__ lw2T,
                       unsigned short* __restrict__ Wf,
                       unsigned short* __restrict__ fw2A) {
    int e = blockIdx.x * 256 + threadIdx.x;
    if (e < 36864) {
        int k = e >> 12, r = e & 4095, o = r >> 6, ci = r & 63;
        cwT[e] = f2bf(cw[o * 576 + ci * 9 + k]);
        return;
    }
    e -= 36864;
    if (e < 27648) {
        int k = e / 3072, r = e % 3072, row = r >> 6, ci = r & 63;
        float v = 0.f;
        if (row < 32) v = lw1[row * 576 + ci * 9 + k];
        else if (row < 41) v = mw[(row - 32) * 576 + ci * 9 + k];
        Wlm[e] = f2bf(v);
        return;
    }
    e -= 27648;
    if (e < 1024) { lw2T[e] = f2bf(lw2[e]); return; }
    e -= 1024;
    if (e < 9216) {
        int k = e >> 10, r = e & 1023, o = r >> 5, cl = r & 31;
        Wf[e] = f2bf(fw1[o * 576 + (32 + cl) * 9 + k]);
        return;
    }
    e -= 9216;
    if (e < 1024) {
        int m = e >> 5, ci = e & 31;
        fw2A[e] = f2bf(m < 18 ? fw2[m * 32 + ci] : 0.f);
    }
}

// ---------------------------------------------------------------------------
// K1: global MLP -> g (B,32), Gsum[b][o][k] = sum_ci g[b,ci]*fuse_w1[o,ci,k]
// ---------------------------------------------------------------------------
__global__ void k_glob(const float* __restrict__ sb,
                       const float* __restrict__ gw1, const float* __restrict__ gb1,
                       const float* __restrict__ gw2, const float* __restrict__ gb2,
                       const float* __restrict__ fw1,
                       float* __restrict__ gsum) {
    __shared__ float g_s[BB * 32];
    int tid = threadIdx.x;  // 128 threads
    if (tid < 128) {
        int b = tid >> 5, i = tid & 31;
        float b0 = sb[b * 5 + 4] - sb[b * 5 + 2];
        float b1 = sb[b * 5 + 3] - sb[b * 5 + 1];
        float acc = gb2[i];
        for (int j = 0; j < 64; ++j) {
            float h1 = b0 * gw1[j * 2 + 0] + b1 * gw1[j * 2 + 1] + gb1[j];
            h1 = fmaxf(h1, 0.f);
            acc += gw2[i * 64 + j] * h1;
        }
        g_s[b * 32 + i] = acc;
    }
    __syncthreads();
    for (int e = tid; e < BB * 32 * 9; e += blockDim.x) {
        int b = e / 288, r = e % 288, o = r / 9, k = r % 9;
        float s = 0.f;
        for (int ci = 0; ci < 32; ++ci)
            s += g_s[b * 32 + ci] * fw1[o * 576 + ci * 9 + k];
        gsum[e] = s;
    }
}

// ---------------------------------------------------------------------------
// K_xT: NCHW f32 -> NHWC bf16 (xT[p*64+ci]); 64px x 64ci LDS-tiled transpose
// ---------------------------------------------------------------------------
__global__ __launch_bounds__(256) void k_xT(const float* __restrict__ x,
                                            unsigned short* __restrict__ xT) {
    __shared__ unsigned short Ls[64 * 66];
    int tid = threadIdx.x;
    int p0 = blockIdx.x * 64;
    int b = p0 / HWP;
    int rem0 = p0 % HWP;
    int px = tid & 63;
    int g4 = tid >> 6;   // 0..3
    const float* xb = x + (size_t)b * CC * HWP + rem0;
#pragma unroll
    for (int it = 0; it < 16; ++it) {
        int ci = it * 4 + g4;
        Ls[px * 66 + ci] = f2bf(xb[(size_t)ci * HWP + px]);
    }
    __syncthreads();
#pragma unroll
    for (int it = 0; it < 16; ++it) {
        int p = it * 4 + g4;
        xT[(size_t)(p0 + p) * 64 + px] = Ls[p * 66 + px];
    }
}

// ---------------------------------------------------------------------------
// K2: loc+mask as MFMA implicit GEMM. Block = 256 thr = 128 px.
// GEMM1: M=48 (32 loc1 + 9 mask + pad), K=576 (9 taps x 64 ci), N=128 px.
// Then relu -> LDS, GEMM2: l = lw2 (32x32) x relu(l1). mask -> sigmoid -> bf16.
// Outputs: lT NHWC bf16 [p][32], mbuf bf16 [k][p].
// ---------------------------------------------------------------------------
__global__ __launch_bounds__(256) void k_locmask(
        const unsigned short* __restrict__ xT,
        const unsigned short* __restrict__ Wlm,
        const unsigned short* __restrict__ lw2T,
        const float* __restrict__ lb1, const float* __restrict__ lb2,
        const float* __restrict__ mb,
        unsigned short* __restrict__ lT, unsigned short* __restrict__ mbuf) {
    __shared__ unsigned short Vs[128 * 72];
    __shared__ unsigned short Ws[48 * 72];
    __shared__ unsigned short VsL[128 * 40];
    __shared__ unsigned short W2[32 * 40];

    int tid = threadIdx.x;
    int p0 = blockIdx.x * 128;
    int rem0 = p0 % HWP;

    int lane = tid & 63, wv = tid >> 6;
    int lr = lane & 15, lq = lane >> 4;
    int n0 = wv * 32;

    int spx = tid >> 1;      // staging pixel 0..127
    int shf = tid & 1;       // ci half
    int sy = (rem0 + spx) / WW;
    int sx = (rem0 + spx) % WW;

    f32x4 acc[3][2];
#pragma unroll
    for (int mt = 0; mt < 3; ++mt)
#pragma unroll
        for (int t = 0; t < 2; ++t) acc[mt][t] = (f32x4){0.f, 0.f, 0.f, 0.f};

    for (int k = 0; k < 9; ++k) {
        int dy = k / 3 - 1, dx = k % 3 - 1;
        __syncthreads();
        // stage A: 48 rows x 64 ci = 384 16B chunks
#pragma unroll
        for (int c = tid; c < 384; c += 256) {
            int row = c >> 3, g = c & 7;
            *(float4*)&Ws[row * 72 + g * 8] =
                *(const float4*)&Wlm[((size_t)k * 48 + row) * 64 + g * 8];
        }
        // stage B: this thread's (px, ci-half) = 4 x 16B
        {
            int yy = sy + dy, xw = sx + dx;
            bool valid = (yy >= 0) && (yy < HH) && (xw >= 0) && (xw < WW);
            unsigned short* dst = &Vs[spx * 72 + shf * 32];
            if (valid) {
                const unsigned short* src =
                    xT + ((size_t)(p0 + spx) + (dy * WW + dx)) * 64 + shf * 32;
#pragma unroll
                for (int j = 0; j < 4; ++j)
                    *(float4*)(dst + j * 8) = *(const float4*)(src + j * 8);
            } else {
                float4 z = {0.f, 0.f, 0.f, 0.f};
#pragma unroll
                for (int j = 0; j < 4; ++j) *(float4*)(dst + j * 8) = z;
            }
        }
        __syncthreads();
#pragma unroll
        for (int h = 0; h < 2; ++h) {
            bf16x8 b0 = *(const bf16x8*)&Vs[(n0 + lr) * 72 + h * 32 + lq * 8];
            bf16x8 b1 = *(const bf16x8*)&Vs[(n0 + 16 + lr) * 72 + h * 32 + lq * 8];
#pragma unroll
            for (int mt = 0; mt < 3; ++mt) {
                bf16x8 a = *(const bf16x8*)&Ws[(mt * 16 + lr) * 72 + h * 32 + lq * 8];
                acc[mt][0] = __builtin_amdgcn_mfma_f32_16x16x32_bf16(a, b0, acc[mt][0], 0, 0, 0);
                acc[mt][1] = __builtin_amdgcn_mfma_f32_16x16x32_bf16(a, b1, acc[mt][1], 0, 0, 0);
            }
        }
    }

    // stage lw2 A while finishing epilogue
#pragma unroll
    for (int c = tid; c < 128; c += 256) {
        int row = c >> 2, g = c & 3;
        *(float4*)&W2[row * 40 + g * 8] = *(const float4*)&lw2T[row * 32 + g * 8];
    }
    // loc1: bias + relu -> VsL[px][m] bf16
#pragma unroll
    for (int mt = 0; mt < 2; ++mt)
#pragma unroll
        for (int t = 0; t < 2; ++t)
#pragma unroll
            for (int r = 0; r < 4; ++r) {
                int m = mt * 16 + lq * 4 + r;
                float v = acc[mt][t][r] + lb1[m];
                VsL[(n0 + t * 16 + lr) * 40 + m] = f2bf(fmaxf(v, 0.f));
            }
    // mask rows (mt=2): sigmoid -> mbuf
#pragma unroll
    for (int t = 0; t < 2; ++t)
#pragma unroll
        for (int r = 0; r < 4; ++r) {
            int j = lq * 4 + r;
            if (j < 9) {
                float v = acc[2][t][r] + mb[j];
                v = 1.f / (1.f + __expf(-v));
                mbuf[(size_t)j * NPIX + p0 + n0 + t * 16 + lr] = f2bf(v);
            }
        }
    __syncthreads();
    // GEMM2: l = lw2 x relu(l1), K=32 (one MFMA step)
    f32x4 acc2[2][2];
#pragma unroll
    for (int mt = 0; mt < 2; ++mt)
#pragma unroll
        for (int t = 0; t < 2; ++t) acc2[mt][t] = (f32x4){0.f, 0.f, 0.f, 0.f};
#pragma unroll
    for (int t = 0; t < 2; ++t) {
        bf16x8 b2 = *(const bf16x8*)&VsL[(n0 + t * 16 + lr) * 40 + lq * 8];
#pragma unroll
        for (int mt = 0; mt < 2; ++mt) {
            bf16x8 a2 = *(const bf16x8*)&W2[(mt * 16 + lr) * 40 + lq * 8];
            acc2[mt][t] = __builtin_amdgcn_mfma_f32_16x16x32_bf16(a2, b2, acc2[mt][t], 0, 0, 0);
        }
    }
    __syncthreads();  // Vs reuse as [px][40] shuffle buffer
#pragma unroll
    for (int mt = 0; mt < 2; ++mt)
#pragma unroll
        for (int t = 0; t < 2; ++t)
#pragma unroll
            for (int r = 0; r < 4; ++r) {
                int m = mt * 16 + lq * 4 + r;
                Vs[(n0 + t * 16 + lr) * 40 + m] = f2bf(acc2[mt][t][r] + lb2[m]);
            }
    __syncthreads();
    // coalesced NHWC store of l
    {
        int px = tid >> 1, hf = tid & 1;
        float4 v0 = *(const float4*)&Vs[px * 40 + hf * 16];
        float4 v1 = *(const float4*)&Vs[px * 40 + hf * 16 + 8];
        unsigned short* dst = lT + (size_t)(p0 + px) * 32 + hf * 16;
        *(float4*)dst = v0;
        *(float4*)(dst + 8) = v1;
    }
}

// ---------------------------------------------------------------------------
// K3: fuse conv as MFMA implicit GEMM. M=32 f, K=288 (9 taps x 32 l-ch), N=128.
// Gsum (g-channel contribution, per-px tap validity) added in epilogue.
// GEMM2: offset = fw2 (18x32 pad 32) x relu(f). Writes ysA/xsA (abs coords).
// ---------------------------------------------------------------------------
__global__ __launch_bounds__(256) void k_fuse(
        const unsigned short* __restrict__ lT,
        const float* __restrict__ gsum,
        const unsigned short* __restrict__ Wf,
        const unsigned short* __restrict__ fw2A,
        const float* __restrict__ fb1, const float* __restrict__ fb2,
        float* __restrict__ ysA, float* __restrict__ xsA) {
    __shared__ unsigned short Vs[128 * 40];
    __shared__ unsigned short Ws[32 * 40];
    __shared__ unsigned short VsF[128 * 40];
    __shared__ unsigned short W2[32 * 40];
    __shared__ float gs[288];

    int tid = threadIdx.x;
    int p0 = blockIdx.x * 128;
    int b = p0 / HWP;
    int rem0 = p0 % HWP;

    int lane = tid & 63, wv = tid >> 6;
    int lr = lane & 15, lq = lane >> 4;
    int n0 = wv * 32;

    int spx = tid >> 1;
    int shf = tid & 1;
    int sy = (rem0 + spx) / WW;
    int sx = (rem0 + spx) % WW;

    for (int e = tid; e < 288; e += 256) gs[e] = gsum[b * 288 + e];

    f32x4 acc[2][2];
#pragma unroll
    for (int mt = 0; mt < 2; ++mt)
#pragma unroll
        for (int t = 0; t < 2; ++t) acc[mt][t] = (f32x4){0.f, 0.f, 0.f, 0.f};

    for (int k = 0; k < 9; ++k) {
        int dy = k / 3 - 1, dx = k % 3 - 1;
        __syncthreads();
#pragma unroll
        for (int c = tid; c < 128; c += 256) {
            int row = c >> 2, g = c & 3;
            *(float4*)&Ws[row * 40 + g * 8] =
                *(const float4*)&Wf[((size_t)k * 32 + row) * 32 + g * 8];
        }
        {
            int yy = sy + dy, xw = sx + dx;
            bool valid = (yy >= 0) && (yy < HH) && (xw >= 0) && (xw < WW);
            unsigned short* dst = &Vs[spx * 40 + shf * 16];
            if (valid) {
                const unsigned short* src =
                    lT + ((size_t)(p0 + spx) + (dy * WW + dx)) * 32 + shf * 16;
                *(float4*)dst = *(const float4*)src;
                *(float4*)(dst + 8) = *(const float4*)(src + 8);
            } else {
                float4 z = {0.f, 0.f, 0.f, 0.f};
                *(float4*)dst = z;
                *(float4*)(dst + 8) = z;
            }
        }
        __syncthreads();
#pragma unroll
        for (int t = 0; t < 2; ++t) {
            bf16x8 bfr = *(const bf16x8*)&Vs[(n0 + t * 16 + lr) * 40 + lq * 8];
#pragma unroll
            for (int mt = 0; mt < 2; ++mt) {
                bf16x8 a = *(const bf16x8*)&Ws[(mt * 16 + lr) * 40 + lq * 8];
                acc[mt][t] = __builtin_amdgcn_mfma_f32_16x16x32_bf16(a, bfr, acc[mt][t], 0, 0, 0);
            }
        }
    }

#pragma unroll
    for (int c = tid; c < 128; c += 256) {
        int row = c >> 2, g = c & 3;
        *(float4*)&W2[row * 40 + g * 8] = *(const float4*)&fw2A[row * 32 + g * 8];
    }
    // epilogue: + fb1 + valid-tap Gsum, relu -> VsF
#pragma unroll
    for (int t = 0; t < 2; ++t) {
        int px = n0 + t * 16 + lr;
        int rem = rem0 + px;
        int y = rem / WW, xx = rem % WW;
        bool vk[9];
#pragma unroll
        for (int k = 0; k < 9; ++k) {
            int yy = y + k / 3 - 1, xw = xx + k % 3 - 1;
            vk[k] = (yy >= 0) && (yy < HH) && (xw >= 0) && (xw < WW);
        }
#pragma unroll
        for (int mt = 0; mt < 2; ++mt)
#pragma unroll
            for (int r = 0; r < 4; ++r) {
                int m = mt * 16 + lq * 4 + r;
                float s = fb1[m];
#pragma unroll
                for (int k = 0; k < 9; ++k)
                    if (vk[k]) s += gs[m * 9 + k];
                float v = acc[mt][t][r] + s;
                VsF[px * 40 + m] = f2bf(fmaxf(v, 0.f));
            }
    }
    __syncthreads();
    f32x4 acc3[2][2];
#pragma unroll
    for (int mt = 0; mt < 2; ++mt)
#pragma unroll
        for (int t = 0; t < 2; ++t) acc3[mt][t] = (f32x4){0.f, 0.f, 0.f, 0.f};
#pragma unroll
    for (int t = 0; t < 2; ++t) {
        bf16x8 b2 = *(const bf16x8*)&VsF[(n0 + t * 16 + lr) * 40 + lq * 8];
#pragma unroll
        for (int mt = 0; mt < 2; ++mt) {
            bf16x8 a2 = *(const bf16x8*)&W2[(mt * 16 + lr) * 40 + lq * 8];
            acc3[mt][t] = __builtin_amdgcn_mfma_f32_16x16x32_bf16(a2, b2, acc3[mt][t], 0, 0, 0);
        }
    }
#pragma unroll
    for (int t = 0; t < 2; ++t) {
        int px = n0 + t * 16 + lr;
        int p = p0 + px;
        int rem = rem0 + px;
        int y = rem / WW, xx = rem % WW;
#pragma unroll
        for (int mt = 0; mt < 2; ++mt)
#pragma unroll
            for (int r = 0; r < 4; ++r) {
                int m = mt * 16 + lq * 4 + r;
                if (m < 18) {
                    int k = m >> 1;
                    float v = acc3[mt][t][r] + fb2[m];
                    if ((m & 1) == 0)
                        ysA[(size_t)k * NPIX + p] = (float)(y + k / 3 - 1) + v;
                    else
                        xsA[(size_t)k * NPIX + p] = (float)(xx + k % 3 - 1) + v;
                }
            }
    }
}

// ---------------------------------------------------------------------------
// K4: deformable conv, MFMA implicit GEMM (R4-verified).
// ---------------------------------------------------------------------------
__global__ __launch_bounds__(256) void k_deform(
        const unsigned short* __restrict__ xT,
        const unsigned short* __restrict__ cwT, const float* __restrict__ cb,
        const float* __restrict__ ysA, const float* __restrict__ xsA,
        const unsigned short* __restrict__ mA, float* __restrict__ out) {
    __shared__ unsigned short Vs[64 * 72];   // [px][ci] pad->72
    __shared__ unsigned short Ws[64 * 72];   // [o][ci]  pad->72
    __shared__ float4 cfA[9 * 64];
    __shared__ int4   igA[9 * 64];

    int tid = threadIdx.x;
    int p0 = blockIdx.x * 64;
    int b = p0 / HWP;
    int rem0 = p0 % HWP;
    const unsigned short* xTb = xT + (size_t)b * HWP * 64;

    for (int e = tid; e < 9 * 64; e += 256) {
        int k = e / 64, px = e % 64;
        int p = p0 + px;
        float ys = ysA[(size_t)k * NPIX + p];
        float xs = xsA[(size_t)k * NPIX + p];
        float mk = bf2f(mA[(size_t)k * NPIX + p]);
        float y0f = floorf(ys), x0f = floorf(xs);
        int y0 = (int)y0f, x0 = (int)x0f;
        float wy = ys - y0f, wx = xs - x0f;
        float c00 = (1.f - wy) * (1.f - wx) * mk;
        float c01 = (1.f - wy) * wx * mk;
        float c10 = wy * (1.f - wx) * mk;
        float c11 = wy * wx * mk;
        bool vy0 = (y0 >= 0) && (y0 < HH);
        bool vy1 = (y0 + 1 >= 0) && (y0 + 1 < HH);
        bool vx0 = (x0 >= 0) && (x0 < WW);
        bool vx1 = (x0 + 1 >= 0) && (x0 + 1 < WW);
        c00 = (vy0 && vx0) ? c00 : 0.f;
        c01 = (vy0 && vx1) ? c01 : 0.f;
        c10 = (vy1 && vx0) ? c10 : 0.f;
        c11 = (vy1 && vx1) ? c11 : 0.f;
        int yc0 = min(max(y0, 0), HH - 1), yc1 = min(max(y0 + 1, 0), HH - 1);
        int xc0 = min(max(x0, 0), WW - 1), xc1 = min(max(x0 + 1, 0), WW - 1);
        cfA[e] = make_float4(c00, c01, c10, c11);
        igA[e] = make_int4((yc0 * WW + xc0) * 64, (yc0 * WW + xc1) * 64,
                           (yc1 * WW + xc0) * 64, (yc1 * WW + xc1) * 64);
    }

    int lane = tid & 63;
    int wv = tid >> 6;
    int m0 = wv * 16;
    int lr = lane & 15;
    int lq = lane >> 4;

    f32x4 cini;
    cini[0] = cb[m0 + lq * 4 + 0];
    cini[1] = cb[m0 + lq * 4 + 1];
    cini[2] = cb[m0 + lq * 4 + 2];
    cini[3] = cb[m0 + lq * 4 + 3];
    f32x4 acc[4];
#pragma unroll
    for (int t = 0; t < 4; ++t) acc[t] = cini;

    int sgc = tid & 15;
    int sci0 = sgc * 4;
    int spx = tid >> 4;

    for (int k = 0; k < 9; ++k) {
        __syncthreads();
#pragma unroll
        for (int c = tid; c < 512; c += 256) {
            int o = c >> 3, g = c & 7;
            *(float4*)&Ws[o * 72 + g * 8] = ((const float4*)(cwT + (size_t)k * 4096))[c];
        }
#pragma unroll
        for (int q = 0; q < 4; ++q) {
            int px = q * 16 + spx;
            float4 cc = cfA[k * 64 + px];
            int4 ii = igA[k * 64 + px];
            ushort4 u00 = *(const ushort4*)&xTb[ii.x + sci0];
            ushort4 u01 = *(const ushort4*)&xTb[ii.y + sci0];
            ushort4 u10 = *(const ushort4*)&xTb[ii.z + sci0];
            ushort4 u11 = *(const ushort4*)&xTb[ii.w + sci0];
            ushort4 r;
            r.x = f2bf(cc.x * bf2f(u00.x) + cc.y * bf2f(u01.x) + cc.z * bf2f(u10.x) + cc.w * bf2f(u11.x));
            r.y = f2bf(cc.x * bf2f(u00.y) + cc.y * bf2f(u01.y) + cc.z * bf2f(u10.y) + cc.w * bf2f(u11.y));
            r.z = f2bf(cc.x * bf2f(u00.z) + cc.y * bf2f(u01.z) + cc.z * bf2f(u10.z) + cc.w * bf2f(u11.z));
            r.w = f2bf(cc.x * bf2f(u00.w) + cc.y * bf2f(u01.w) + cc.z * bf2f(u10.w) + cc.w * bf2f(u11.w));
            *(ushort4*)&Vs[px * 72 + sci0] = r;
        }
        __syncthreads();
        bf16x8 a0 = *(const bf16x8*)&Ws[(m0 + lr) * 72 + lq * 8];
        bf16x8 a1 = *(const bf16x8*)&Ws[(m0 + lr) * 72 + 32 + lq * 8];
#pragma unroll
        for (int t = 0; t < 4; ++t) {
            bf16x8 b0 = *(const bf16x8*)&Vs[(t * 16 + lr) * 72 + lq * 8];
            bf16x8 b1 = *(const bf16x8*)&Vs[(t * 16 + lr) * 72 + 32 + lq * 8];
            acc[t] = __builtin_amdgcn_mfma_f32_16x16x32_bf16(a0, b0, acc[t], 0, 0, 0);
            acc[t] = __builtin_amdgcn_mfma_f32_16x16x32_bf16(a1, b1, acc[t], 0, 0, 0);
        }
    }

#pragma unroll
    for (int t = 0; t < 4; ++t) {
#pragma unroll
        for (int r = 0; r < 4; ++r) {
            int o = m0 + lq * 4 + r;
            out[(size_t)(b * 64 + o) * HWP + rem0 + t * 16 + lr] = acc[t][r];
        }
    }
}

// ---------------------------------------------------------------------------
extern "C" void kernel_launch(void* const* d_in, const int* in_sizes, int n_in,
                              void* d_out, int out_size, void* d_ws, size_t ws_size,
                              hipStream_t stream) {
    const float* x   = (const float*)d_in[0];
    const float* sb  = (const float*)d_in[1];
    const float* gw1 = (const float*)d_in[2];
    const float* gb1 = (const float*)d_in[3];
    const float* gw2 = (const float*)d_in[4];
    const float* gb2 = (const float*)d_in[5];
    const float* lw1 = (const float*)d_in[6];
    const float* lb1 = (const float*)d_in[7];
    const float* lw2 = (const float*)d_in[8];
    const float* lb2 = (const float*)d_in[9];
    const float* fw1 = (const float*)d_in[10];
    const float* fb1 = (const float*)d_in[11];
    const float* fw2 = (const float*)d_in[12];
    const float* fb2 = (const float*)d_in[13];
    const float* mw  = (const float*)d_in[14];
    const float* mb  = (const float*)d_in[15];
    const float* cw  = (const float*)d_in[16];
    const float* cb  = (const float*)d_in[17];
    float* out = (float*)d_out;

    char* w = (char*)d_ws;
    float* gsum = (float*)w;                 w += 1152 * 4;
    unsigned short* cwT  = (unsigned short*)w; w += 36864 * 2;
    unsigned short* Wlm  = (unsigned short*)w; w += 27648 * 2;
    unsigned short* lw2T = (unsigned short*)w; w += 1024 * 2;
    unsigned short* Wf   = (unsigned short*)w; w += 9216 * 2;
    unsigned short* fw2A = (unsigned short*)w; w += 1024 * 2;
    unsigned short* mbuf = (unsigned short*)w; w += (size_t)9 * NPIX * 2;
    float* ysA = (float*)w;                  w += (size_t)9 * NPIX * 4;
    float* xsA = (float*)w;                  w += (size_t)9 * NPIX * 4;
    unsigned short* xT = (unsigned short*)w; w += (size_t)NPIX * 64 * 2;
    unsigned short* lT = (unsigned short*)w;

    k_prep<<<(PREP_N + 255) / 256, 256, 0, stream>>>(cw, lw1, mw, lw2, fw1, fw2,
                                                     cwT, Wlm, lw2T, Wf, fw2A);
    k_glob<<<1, 128, 0, stream>>>(sb, gw1, gb1, gw2, gb2, fw1, gsum);
    k_xT<<<NPIX / 64, 256, 0, stream>>>(x, xT);
    k_locmask<<<NPIX / 128, 256, 0, stream>>>(xT, Wlm, lw2T, lb1, lb2, mb, lT, mbuf);
    k_fuse<<<NPIX / 128, 256, 0, stream>>>(lT, gsum, Wf, fw2A, fb1, fb2, ysA, xsA);
    k_deform<<<NPIX / 64, 256, 0, stream>>>(xT, cwT, cb, ysA, xsA, mbuf, out);
}

// Round 9
// 214.979 us; speedup vs baseline: 1.3664x; 1.0077x over previous
//
#include <hip/hip_runtime.h>
#include <hip/hip_bf16.h>
#include <math.h>

#define BB 4
#define CC 64
#define OO 64
#define HH 96
#define WW 320
#define HWP (HH*WW)   // 30720
#define NPIX (BB*HWP) // 122880

typedef __attribute__((ext_vector_type(8))) short bf16x8;
typedef __attribute__((ext_vector_type(8))) unsigned short u16x8;
typedef __attribute__((ext_vector_type(4))) float f32x4;

__device__ inline unsigned short f2bf(float f) {
    unsigned int u = __float_as_uint(f);
    u = (u + 0x7FFFu + ((u >> 16) & 1u)) >> 16;
    return (unsigned short)u;
}
__device__ inline float bf2f(unsigned short s) {
    return __uint_as_float(((unsigned int)s) << 16);
}
// pack two interp results as adjacent bf16 (truncating): 3 VALU ops
__device__ inline unsigned int pack2bf(float lo, float hi) {
    return (__float_as_uint(lo) >> 16) | (__float_as_uint(hi) & 0xffff0000u);
}

// ---------------------------------------------------------------------------
// K_prep: all bf16 weight repacks in one launch.  [R8-verified]
// ---------------------------------------------------------------------------
#define PREP_N (36864 + 27648 + 1024 + 9216 + 1024)
__global__ void k_prep(const float* __restrict__ cw,
                       const float* __restrict__ lw1, const float* __restrict__ mw,
                       const float* __restrict__ lw2,
                       const float* __restrict__ fw1, const float* __restrict__ fw2,
                       unsigned short* __restrict__ cwT,
                       unsigned short* __restrict__ Wlm,
                       unsigned short* __restrict__ lw2T,
                       unsigned short* __restrict__ Wf,
                       unsigned short* __restrict__ fw2A) {
    int e = blockIdx.x * 256 + threadIdx.x;
    if (e < 36864) {
        int k = e >> 12, r = e & 4095, o = r >> 6, ci = r & 63;
        cwT[e] = f2bf(cw[o * 576 + ci * 9 + k]);
        return;
    }
    e -= 36864;
    if (e < 27648) {
        int k = e / 3072, r = e % 3072, row = r >> 6, ci = r & 63;
        float v = 0.f;
        if (row < 32) v = lw1[row * 576 + ci * 9 + k];
        else if (row < 41) v = mw[(row - 32) * 576 + ci * 9 + k];
        Wlm[e] = f2bf(v);
        return;
    }
    e -= 27648;
    if (e < 1024) { lw2T[e] = f2bf(lw2[e]); return; }
    e -= 1024;
    if (e < 9216) {
        int k = e >> 10, r = e & 1023, o = r >> 5, cl = r & 31;
        Wf[e] = f2bf(fw1[o * 576 + (32 + cl) * 9 + k]);
        return;
    }
    e -= 9216;
    if (e < 1024) {
        int m = e >> 5, ci = e & 31;
        fw2A[e] = f2bf(m < 18 ? fw2[m * 32 + ci] : 0.f);
    }
}

// ---------------------------------------------------------------------------
// K1: global MLP -> Gsum.  [R8-verified]
// ---------------------------------------------------------------------------
__global__ void k_glob(const float* __restrict__ sb,
                       const float* __restrict__ gw1, const float* __restrict__ gb1,
                       const float* __restrict__ gw2, const float* __restrict__ gb2,
                       const float* __restrict__ fw1,
                       float* __restrict__ gsum) {
    __shared__ float g_s[BB * 32];
    int tid = threadIdx.x;  // 128 threads
    if (tid < 128) {
        int b = tid >> 5, i = tid & 31;
        float b0 = sb[b * 5 + 4] - sb[b * 5 + 2];
        float b1 = sb[b * 5 + 3] - sb[b * 5 + 1];
        float acc = gb2[i];
        for (int j = 0; j < 64; ++j) {
            float h1 = b0 * gw1[j * 2 + 0] + b1 * gw1[j * 2 + 1] + gb1[j];
            h1 = fmaxf(h1, 0.f);
            acc += gw2[i * 64 + j] * h1;
        }
        g_s[b * 32 + i] = acc;
    }
    __syncthreads();
    for (int e = tid; e < BB * 32 * 9; e += blockDim.x) {
        int b = e / 288, r = e % 288, o = r / 9, k = r % 9;
        float s = 0.f;
        for (int ci = 0; ci < 32; ++ci)
            s += g_s[b * 32 + ci] * fw1[o * 576 + ci * 9 + k];
        gsum[e] = s;
    }
}

// ---------------------------------------------------------------------------
// K_xT: NCHW f32 -> NHWC bf16.  [R8-verified]
// ---------------------------------------------------------------------------
__global__ __launch_bounds__(256) void k_xT(const float* __restrict__ x,
                                            unsigned short* __restrict__ xT) {
    __shared__ unsigned short Ls[64 * 66];
    int tid = threadIdx.x;
    int p0 = blockIdx.x * 64;
    int b = p0 / HWP;
    int rem0 = p0 % HWP;
    int px = tid & 63;
    int g4 = tid >> 6;   // 0..3
    const float* xb = x + (size_t)b * CC * HWP + rem0;
#pragma unroll
    for (int it = 0; it < 16; ++it) {
        int ci = it * 4 + g4;
        Ls[px * 66 + ci] = f2bf(xb[(size_t)ci * HWP + px]);
    }
    __syncthreads();
#pragma unroll
    for (int it = 0; it < 16; ++it) {
        int p = it * 4 + g4;
        xT[(size_t)(p0 + p) * 64 + px] = Ls[p * 66 + px];
    }
}

// ---------------------------------------------------------------------------
// K2: loc+mask MFMA implicit GEMM.  [R8-verified]
// ---------------------------------------------------------------------------
__global__ __launch_bounds__(256) void k_locmask(
        const unsigned short* __restrict__ xT,
        const unsigned short* __restrict__ Wlm,
        const unsigned short* __restrict__ lw2T,
        const float* __restrict__ lb1, const float* __restrict__ lb2,
        const float* __restrict__ mb,
        unsigned short* __restrict__ lT, unsigned short* __restrict__ mbuf) {
    __shared__ unsigned short Vs[128 * 72];
    __shared__ unsigned short Ws[48 * 72];
    __shared__ unsigned short VsL[128 * 40];
    __shared__ unsigned short W2[32 * 40];

    int tid = threadIdx.x;
    int p0 = blockIdx.x * 128;
    int rem0 = p0 % HWP;

    int lane = tid & 63, wv = tid >> 6;
    int lr = lane & 15, lq = lane >> 4;
    int n0 = wv * 32;

    int spx = tid >> 1;      // staging pixel 0..127
    int shf = tid & 1;       // ci half
    int sy = (rem0 + spx) / WW;
    int sx = (rem0 + spx) % WW;

    f32x4 acc[3][2];
#pragma unroll
    for (int mt = 0; mt < 3; ++mt)
#pragma unroll
        for (int t = 0; t < 2; ++t) acc[mt][t] = (f32x4){0.f, 0.f, 0.f, 0.f};

    for (int k = 0; k < 9; ++k) {
        int dy = k / 3 - 1, dx = k % 3 - 1;
        __syncthreads();
        // stage A: 48 rows x 64 ci = 384 16B chunks
#pragma unroll
        for (int c = tid; c < 384; c += 256) {
            int row = c >> 3, g = c & 7;
            *(float4*)&Ws[row * 72 + g * 8] =
                *(const float4*)&Wlm[((size_t)k * 48 + row) * 64 + g * 8];
        }
        // stage B: this thread's (px, ci-half) = 4 x 16B
        {
            int yy = sy + dy, xw = sx + dx;
            bool valid = (yy >= 0) && (yy < HH) && (xw >= 0) && (xw < WW);
            unsigned short* dst = &Vs[spx * 72 + shf * 32];
            if (valid) {
                const unsigned short* src =
                    xT + ((size_t)(p0 + spx) + (dy * WW + dx)) * 64 + shf * 32;
#pragma unroll
                for (int j = 0; j < 4; ++j)
                    *(float4*)(dst + j * 8) = *(const float4*)(src + j * 8);
            } else {
                float4 z = {0.f, 0.f, 0.f, 0.f};
#pragma unroll
                for (int j = 0; j < 4; ++j) *(float4*)(dst + j * 8) = z;
            }
        }
        __syncthreads();
#pragma unroll
        for (int h = 0; h < 2; ++h) {
            bf16x8 b0 = *(const bf16x8*)&Vs[(n0 + lr) * 72 + h * 32 + lq * 8];
            bf16x8 b1 = *(const bf16x8*)&Vs[(n0 + 16 + lr) * 72 + h * 32 + lq * 8];
#pragma unroll
            for (int mt = 0; mt < 3; ++mt) {
                bf16x8 a = *(const bf16x8*)&Ws[(mt * 16 + lr) * 72 + h * 32 + lq * 8];
                acc[mt][0] = __builtin_amdgcn_mfma_f32_16x16x32_bf16(a, b0, acc[mt][0], 0, 0, 0);
                acc[mt][1] = __builtin_amdgcn_mfma_f32_16x16x32_bf16(a, b1, acc[mt][1], 0, 0, 0);
            }
        }
    }

    // stage lw2 A while finishing epilogue
#pragma unroll
    for (int c = tid; c < 128; c += 256) {
        int row = c >> 2, g = c & 3;
        *(float4*)&W2[row * 40 + g * 8] = *(const float4*)&lw2T[row * 32 + g * 8];
    }
    // loc1: bias + relu -> VsL[px][m] bf16
#pragma unroll
    for (int mt = 0; mt < 2; ++mt)
#pragma unroll
        for (int t = 0; t < 2; ++t)
#pragma unroll
            for (int r = 0; r < 4; ++r) {
                int m = mt * 16 + lq * 4 + r;
                float v = acc[mt][t][r] + lb1[m];
                VsL[(n0 + t * 16 + lr) * 40 + m] = f2bf(fmaxf(v, 0.f));
            }
    // mask rows (mt=2): sigmoid -> mbuf
#pragma unroll
    for (int t = 0; t < 2; ++t)
#pragma unroll
        for (int r = 0; r < 4; ++r) {
            int j = lq * 4 + r;
            if (j < 9) {
                float v = acc[2][t][r] + mb[j];
                v = 1.f / (1.f + __expf(-v));
                mbuf[(size_t)j * NPIX + p0 + n0 + t * 16 + lr] = f2bf(v);
            }
        }
    __syncthreads();
    // GEMM2: l = lw2 x relu(l1), K=32 (one MFMA step)
    f32x4 acc2[2][2];
#pragma unroll
    for (int mt = 0; mt < 2; ++mt)
#pragma unroll
        for (int t = 0; t < 2; ++t) acc2[mt][t] = (f32x4){0.f, 0.f, 0.f, 0.f};
#pragma unroll
    for (int t = 0; t < 2; ++t) {
        bf16x8 b2 = *(const bf16x8*)&VsL[(n0 + t * 16 + lr) * 40 + lq * 8];
#pragma unroll
        for (int mt = 0; mt < 2; ++mt) {
            bf16x8 a2 = *(const bf16x8*)&W2[(mt * 16 + lr) * 40 + lq * 8];
            acc2[mt][t] = __builtin_amdgcn_mfma_f32_16x16x32_bf16(a2, b2, acc2[mt][t], 0, 0, 0);
        }
    }
    __syncthreads();  // Vs reuse as [px][40] shuffle buffer
#pragma unroll
    for (int mt = 0; mt < 2; ++mt)
#pragma unroll
        for (int t = 0; t < 2; ++t)
#pragma unroll
            for (int r = 0; r < 4; ++r) {
                int m = mt * 16 + lq * 4 + r;
                Vs[(n0 + t * 16 + lr) * 40 + m] = f2bf(acc2[mt][t][r] + lb2[m]);
            }
    __syncthreads();
    // coalesced NHWC store of l
    {
        int px = tid >> 1, hf = tid & 1;
        float4 v0 = *(const float4*)&Vs[px * 40 + hf * 16];
        float4 v1 = *(const float4*)&Vs[px * 40 + hf * 16 + 8];
        unsigned short* dst = lT + (size_t)(p0 + px) * 32 + hf * 16;
        *(float4*)dst = v0;
        *(float4*)(dst + 8) = v1;
    }
}

// ---------------------------------------------------------------------------
// K3: fuse conv MFMA implicit GEMM -> ysA/xsA.  [R8-verified]
// ---------------------------------------------------------------------------
__global__ __launch_bounds__(256) void k_fuse(
        const unsigned short* __restrict__ lT,
        const float* __restrict__ gsum,
        const unsigned short* __restrict__ Wf,
        const unsigned short* __restrict__ fw2A,
        const float* __restrict__ fb1, const float* __restrict__ fb2,
        float* __restrict__ ysA, float* __restrict__ xsA) {
    __shared__ unsigned short Vs[128 * 40];
    __shared__ unsigned short Ws[32 * 40];
    __shared__ unsigned short VsF[128 * 40];
    __shared__ unsigned short W2[32 * 40];
    __shared__ float gs[288];

    int tid = threadIdx.x;
    int p0 = blockIdx.x * 128;
    int b = p0 / HWP;
    int rem0 = p0 % HWP;

    int lane = tid & 63, wv = tid >> 6;
    int lr = lane & 15, lq = lane >> 4;
    int n0 = wv * 32;

    int spx = tid >> 1;
    int shf = tid & 1;
    int sy = (rem0 + spx) / WW;
    int sx = (rem0 + spx) % WW;

    for (int e = tid; e < 288; e += 256) gs[e] = gsum[b * 288 + e];

    f32x4 acc[2][2];
#pragma unroll
    for (int mt = 0; mt < 2; ++mt)
#pragma unroll
        for (int t = 0; t < 2; ++t) acc[mt][t] = (f32x4){0.f, 0.f, 0.f, 0.f};

    for (int k = 0; k < 9; ++k) {
        int dy = k / 3 - 1, dx = k % 3 - 1;
        __syncthreads();
#pragma unroll
        for (int c = tid; c < 128; c += 256) {
            int row = c >> 2, g = c & 3;
            *(float4*)&Ws[row * 40 + g * 8] =
                *(const float4*)&Wf[((size_t)k * 32 + row) * 32 + g * 8];
        }
        {
            int yy = sy + dy, xw = sx + dx;
            bool valid = (yy >= 0) && (yy < HH) && (xw >= 0) && (xw < WW);
            unsigned short* dst = &Vs[spx * 40 + shf * 16];
            if (valid) {
                const unsigned short* src =
                    lT + ((size_t)(p0 + spx) + (dy * WW + dx)) * 32 + shf * 16;
                *(float4*)dst = *(const float4*)src;
                *(float4*)(dst + 8) = *(const float4*)(src + 8);
            } else {
                float4 z = {0.f, 0.f, 0.f, 0.f};
                *(float4*)dst = z;
                *(float4*)(dst + 8) = z;
            }
        }
        __syncthreads();
#pragma unroll
        for (int t = 0; t < 2; ++t) {
            bf16x8 bfr = *(const bf16x8*)&Vs[(n0 + t * 16 + lr) * 40 + lq * 8];
#pragma unroll
            for (int mt = 0; mt < 2; ++mt) {
                bf16x8 a = *(const bf16x8*)&Ws[(mt * 16 + lr) * 40 + lq * 8];
                acc[mt][t] = __builtin_amdgcn_mfma_f32_16x16x32_bf16(a, bfr, acc[mt][t], 0, 0, 0);
            }
        }
    }

#pragma unroll
    for (int c = tid; c < 128; c += 256) {
        int row = c >> 2, g = c & 3;
        *(float4*)&W2[row * 40 + g * 8] = *(const float4*)&fw2A[row * 32 + g * 8];
    }
    // epilogue: + fb1 + valid-tap Gsum, relu -> VsF
#pragma unroll
    for (int t = 0; t < 2; ++t) {
        int px = n0 + t * 16 + lr;
        int rem = rem0 + px;
        int y = rem / WW, xx = rem % WW;
        bool vk[9];
#pragma unroll
        for (int k = 0; k < 9; ++k) {
            int yy = y + k / 3 - 1, xw = xx + k % 3 - 1;
            vk[k] = (yy >= 0) && (yy < HH) && (xw >= 0) && (xw < WW);
        }
#pragma unroll
        for (int mt = 0; mt < 2; ++mt)
#pragma unroll
            for (int r = 0; r < 4; ++r) {
                int m = mt * 16 + lq * 4 + r;
                float s = fb1[m];
#pragma unroll
                for (int k = 0; k < 9; ++k)
                    if (vk[k]) s += gs[m * 9 + k];
                float v = acc[mt][t][r] + s;
                VsF[px * 40 + m] = f2bf(fmaxf(v, 0.f));
            }
    }
    __syncthreads();
    f32x4 acc3[2][2];
#pragma unroll
    for (int mt = 0; mt < 2; ++mt)
#pragma unroll
        for (int t = 0; t < 2; ++t) acc3[mt][t] = (f32x4){0.f, 0.f, 0.f, 0.f};
#pragma unroll
    for (int t = 0; t < 2; ++t) {
        bf16x8 b2 = *(const bf16x8*)&VsF[(n0 + t * 16 + lr) * 40 + lq * 8];
#pragma unroll
        for (int mt = 0; mt < 2; ++mt) {
            bf16x8 a2 = *(const bf16x8*)&W2[(mt * 16 + lr) * 40 + lq * 8];
            acc3[mt][t] = __builtin_amdgcn_mfma_f32_16x16x32_bf16(a2, b2, acc3[mt][t], 0, 0, 0);
        }
    }
#pragma unroll
    for (int t = 0; t < 2; ++t) {
        int px = n0 + t * 16 + lr;
        int p = p0 + px;
        int rem = rem0 + px;
        int y = rem / WW, xx = rem % WW;
#pragma unroll
        for (int mt = 0; mt < 2; ++mt)
#pragma unroll
            for (int r = 0; r < 4; ++r) {
                int m = mt * 16 + lq * 4 + r;
                if (m < 18) {
                    int k = m >> 1;
                    float v = acc3[mt][t][r] + fb2[m];
                    if ((m & 1) == 0)
                        ysA[(size_t)k * NPIX + p] = (float)(y + k / 3 - 1) + v;
                    else
                        xsA[(size_t)k * NPIX + p] = (float)(xx + k % 3 - 1) + v;
                }
            }
    }
}

// ---------------------------------------------------------------------------
// K4: deformable conv, MFMA implicit GEMM (R8-verified structure).
// DELTA R9: interp-result cvt+pack is now truncating pack2bf (3 ops / 2 elems)
// instead of per-element RNE f2bf + ushort4 assembly. Same addresses, same
// layout, same barriers.
// ---------------------------------------------------------------------------
__global__ __launch_bounds__(256) void k_deform(
        const unsigned short* __restrict__ xT,
        const unsigned short* __restrict__ cwT, const float* __restrict__ cb,
        const float* __restrict__ ysA, const float* __restrict__ xsA,
        const unsigned short* __restrict__ mA, float* __restrict__ out) {
    __shared__ unsigned short Vs[64 * 72];   // [px][ci] pad->72
    __shared__ unsigned short Ws[64 * 72];   // [o][ci]  pad->72
    __shared__ float4 cfA[9 * 64];
    __shared__ int4   igA[9 * 64];

    int tid = threadIdx.x;
    int p0 = blockIdx.x * 64;
    int b = p0 / HWP;
    int rem0 = p0 % HWP;
    const unsigned short* xTb = xT + (size_t)b * HWP * 64;

    for (int e = tid; e < 9 * 64; e += 256) {
        int k = e / 64, px = e % 64;
        int p = p0 + px;
        float ys = ysA[(size_t)k * NPIX + p];
        float xs = xsA[(size_t)k * NPIX + p];
        float mk = bf2f(mA[(size_t)k * NPIX + p]);
        float y0f = floorf(ys), x0f = floorf(xs);
        int y0 = (int)y0f, x0 = (int)x0f;
        float wy = ys - y0f, wx = xs - x0f;
        float c00 = (1.f - wy) * (1.f - wx) * mk;
        float c01 = (1.f - wy) * wx * mk;
        float c10 = wy * (1.f - wx) * mk;
        float c11 = wy * wx * mk;
        bool vy0 = (y0 >= 0) && (y0 < HH);
        bool vy1 = (y0 + 1 >= 0) && (y0 + 1 < HH);
        bool vx0 = (x0 >= 0) && (x0 < WW);
        bool vx1 = (x0 + 1 >= 0) && (x0 + 1 < WW);
        c00 = (vy0 && vx0) ? c00 : 0.f;
        c01 = (vy0 && vx1) ? c01 : 0.f;
        c10 = (vy1 && vx0) ? c10 : 0.f;
        c11 = (vy1 && vx1) ? c11 : 0.f;
        int yc0 = min(max(y0, 0), HH - 1), yc1 = min(max(y0 + 1, 0), HH - 1);
        int xc0 = min(max(x0, 0), WW - 1), xc1 = min(max(x0 + 1, 0), WW - 1);
        cfA[e] = make_float4(c00, c01, c10, c11);
        igA[e] = make_int4((yc0 * WW + xc0) * 64, (yc0 * WW + xc1) * 64,
                           (yc1 * WW + xc0) * 64, (yc1 * WW + xc1) * 64);
    }

    int lane = tid & 63;
    int wv = tid >> 6;
    int m0 = wv * 16;
    int lr = lane & 15;
    int lq = lane >> 4;

    f32x4 cini;
    cini[0] = cb[m0 + lq * 4 + 0];
    cini[1] = cb[m0 + lq * 4 + 1];
    cini[2] = cb[m0 + lq * 4 + 2];
    cini[3] = cb[m0 + lq * 4 + 3];
    f32x4 acc[4];
#pragma unroll
    for (int t = 0; t < 4; ++t) acc[t] = cini;

    int sgc = tid & 15;
    int sci0 = sgc * 4;
    int spx = tid >> 4;

    for (int k = 0; k < 9; ++k) {
        __syncthreads();
#pragma unroll
        for (int c = tid; c < 512; c += 256) {
            int o = c >> 3, g = c & 7;
            *(float4*)&Ws[o * 72 + g * 8] = ((const float4*)(cwT + (size_t)k * 4096))[c];
        }
#pragma unroll
        for (int q = 0; q < 4; ++q) {
            int px = q * 16 + spx;
            float4 cc = cfA[k * 64 + px];
            int4 ii = igA[k * 64 + px];
            ushort4 u00 = *(const ushort4*)&xTb[ii.x + sci0];
            ushort4 u01 = *(const ushort4*)&xTb[ii.y + sci0];
            ushort4 u10 = *(const ushort4*)&xTb[ii.z + sci0];
            ushort4 u11 = *(const ushort4*)&xTb[ii.w + sci0];
            float v0 = cc.x * bf2f(u00.x) + cc.y * bf2f(u01.x) + cc.z * bf2f(u10.x) + cc.w * bf2f(u11.x);
            float v1 = cc.x * bf2f(u00.y) + cc.y * bf2f(u01.y) + cc.z * bf2f(u10.y) + cc.w * bf2f(u11.y);
            float v2 = cc.x * bf2f(u00.z) + cc.y * bf2f(u01.z) + cc.z * bf2f(u10.z) + cc.w * bf2f(u11.z);
            float v3 = cc.x * bf2f(u00.w) + cc.y * bf2f(u01.w) + cc.z * bf2f(u10.w) + cc.w * bf2f(u11.w);
            uint2 r;
            r.x = pack2bf(v0, v1);
            r.y = pack2bf(v2, v3);
            *(uint2*)&Vs[px * 72 + sci0] = r;
        }
        __syncthreads();
        bf16x8 a0 = *(const bf16x8*)&Ws[(m0 + lr) * 72 + lq * 8];
        bf16x8 a1 = *(const bf16x8*)&Ws[(m0 + lr) * 72 + 32 + lq * 8];
#pragma unroll
        for (int t = 0; t < 4; ++t) {
            bf16x8 b0 = *(const bf16x8*)&Vs[(t * 16 + lr) * 72 + lq * 8];
            bf16x8 b1 = *(const bf16x8*)&Vs[(t * 16 + lr) * 72 + 32 + lq * 8];
            acc[t] = __builtin_amdgcn_mfma_f32_16x16x32_bf16(a0, b0, acc[t], 0, 0, 0);
            acc[t] = __builtin_amdgcn_mfma_f32_16x16x32_bf16(a1, b1, acc[t], 0, 0, 0);
        }
    }

#pragma unroll
    for (int t = 0; t < 4; ++t) {
#pragma unroll
        for (int r = 0; r < 4; ++r) {
            int o = m0 + lq * 4 + r;
            out[(size_t)(b * 64 + o) * HWP + rem0 + t * 16 + lr] = acc[t][r];
        }
    }
}

// ---------------------------------------------------------------------------
extern "C" void kernel_launch(void* const* d_in, const int* in_sizes, int n_in,
                              void* d_out, int out_size, void* d_ws, size_t ws_size,
                              hipStream_t stream) {
    const float* x   = (const float*)d_in[0];
    const float* sb  = (const float*)d_in[1];
    const float* gw1 = (const float*)d_in[2];
    const float* gb1 = (const float*)d_in[3];
    const float* gw2 = (const float*)d_in[4];
    const float* gb2 = (const float*)d_in[5];
    const float* lw1 = (const float*)d_in[6];
    const float* lb1 = (const float*)d_in[7];
    const float* lw2 = (const float*)d_in[8];
    const float* lb2 = (const float*)d_in[9];
    const float* fw1 = (const float*)d_in[10];
    const float* fb1 = (const float*)d_in[11];
    const float* fw2 = (const float*)d_in[12];
    const float* fb2 = (const float*)d_in[13];
    const float* mw  = (const float*)d_in[14];
    const float* mb  = (const float*)d_in[15];
    const float* cw  = (const float*)d_in[16];
    const float* cb  = (const float*)d_in[17];
    float* out = (float*)d_out;

    char* w = (char*)d_ws;
    float* gsum = (float*)w;                 w += 1152 * 4;
    unsigned short* cwT  = (unsigned short*)w; w += 36864 * 2;
    unsigned short* Wlm  = (unsigned short*)w; w += 27648 * 2;
    unsigned short* lw2T = (unsigned short*)w; w += 1024 * 2;
    unsigned short* Wf   = (unsigned short*)w; w += 9216 * 2;
    unsigned short* fw2A = (unsigned short*)w; w += 1024 * 2;
    unsigned short* mbuf = (unsigned short*)w; w += (size_t)9 * NPIX * 2;
    float* ysA = (float*)w;                  w += (size_t)9 * NPIX * 4;
    float* xsA = (float*)w;                  w += (size_t)9 * NPIX * 4;
    unsigned short* xT = (unsigned short*)w; w += (size_t)NPIX * 64 * 2;
    unsigned short* lT = (unsigned short*)w;

    k_prep<<<(PREP_N + 255) / 256, 256, 0, stream>>>(cw, lw1, mw, lw2, fw1, fw2,
                                                     cwT, Wlm, lw2T, Wf, fw2A);
    k_glob<<<1, 128, 0, stream>>>(sb, gw1, gb1, gw2, gb2, fw1, gsum);
    k_xT<<<NPIX / 64, 256, 0, stream>>>(x, xT);
    k_locmask<<<NPIX / 128, 256, 0, stream>>>(xT, Wlm, lw2T, lb1, lb2, mb, lT, mbuf);
    k_fuse<<<NPIX / 128, 256, 0, stream>>>(lT, gsum, Wf, fw2A, fb1, fb2, ysA, xsA);
    k_deform<<<NPIX / 64, 256, 0, stream>>>(xT, cwT, cb, ysA, xsA, mbuf, out);
}